// Round 1
// baseline (71268.250 us; speedup 1.0000x reference)
//
#include <hip/hip_runtime.h>
#include <cstdint>

// Problem constants: B=16, T=2048, H=1024, 3H=3072.
// ws layout: gi (bf16, [T][B][3H]) 201326592 B | hpub (fp32, [2][16][1024]) 131072 B | flags 16384 B

using short8 = __attribute__((ext_vector_type(8))) short;
using f32x4v = __attribute__((ext_vector_type(4))) float;

__device__ __forceinline__ unsigned short f2bf(float f) {
  unsigned u = __float_as_uint(f);
  unsigned r = (u + 0x7FFFu + ((u >> 16) & 1u)) >> 16;  // RNE
  return (unsigned short)r;
}
__device__ __forceinline__ float bf2f(unsigned short s) {
  return __uint_as_float(((unsigned)s) << 16);
}

// ---------------------------------------------------------------------------
// Kernel 1: gi = h_enc @ w_ih^T + b_ih   (bf16 MFMA, inline fp32->bf16 staging)
// A = h_enc [M=32768][K=1024] fp32 (m = b*2048 + t), B = w_ih [N=3072][K=1024] fp32
// C stored bf16 at gi[(t*16 + b)*3072 + n]
// ---------------------------------------------------------------------------
__global__ __launch_bounds__(256) void gi_gemm(const float* __restrict__ A,
                                               const float* __restrict__ W,
                                               const float* __restrict__ bih,
                                               unsigned short* __restrict__ gi) {
  __shared__ unsigned short As[128 * 40];  // 128 rows x 32 bf16, stride 40 (16B-aligned pad)
  __shared__ unsigned short Bs[128 * 40];
  const int tid = threadIdx.x;
  const int bm = blockIdx.x, bn = blockIdx.y;
  const int row = tid >> 1, colg = (tid & 1) * 16;
  const float* Ap = A + (size_t)(bm * 128 + row) * 1024 + colg;
  const float* Bp = W + (size_t)(bn * 128 + row) * 1024 + colg;
  float4 ar[4], br[4];
#pragma unroll
  for (int q = 0; q < 4; ++q) {
    ar[q] = *(const float4*)(Ap + q * 4);
    br[q] = *(const float4*)(Bp + q * 4);
  }
  const int lane = tid & 63, wid = tid >> 6;
  const int quad = lane >> 4, l15 = lane & 15;
  const int wm = (wid >> 1) * 64, wn = (wid & 1) * 64;
  f32x4v acc[4][4];
#pragma unroll
  for (int i = 0; i < 4; ++i)
#pragma unroll
    for (int j = 0; j < 4; ++j) acc[i][j] = (f32x4v){0.f, 0.f, 0.f, 0.f};

#pragma unroll 1
  for (int kt = 0; kt < 32; ++kt) {
    __syncthreads();
    {
      alignas(16) unsigned short tmp[16];
#pragma unroll
      for (int q = 0; q < 4; ++q) {
        tmp[q * 4 + 0] = f2bf(ar[q].x); tmp[q * 4 + 1] = f2bf(ar[q].y);
        tmp[q * 4 + 2] = f2bf(ar[q].z); tmp[q * 4 + 3] = f2bf(ar[q].w);
      }
      *(short8*)&As[row * 40 + colg]     = *(short8*)&tmp[0];
      *(short8*)&As[row * 40 + colg + 8] = *(short8*)&tmp[8];
#pragma unroll
      for (int q = 0; q < 4; ++q) {
        tmp[q * 4 + 0] = f2bf(br[q].x); tmp[q * 4 + 1] = f2bf(br[q].y);
        tmp[q * 4 + 2] = f2bf(br[q].z); tmp[q * 4 + 3] = f2bf(br[q].w);
      }
      *(short8*)&Bs[row * 40 + colg]     = *(short8*)&tmp[0];
      *(short8*)&Bs[row * 40 + colg + 8] = *(short8*)&tmp[8];
    }
    __syncthreads();
    if (kt < 31) {
      Ap += 32; Bp += 32;
#pragma unroll
      for (int q = 0; q < 4; ++q) {
        ar[q] = *(const float4*)(Ap + q * 4);
        br[q] = *(const float4*)(Bp + q * 4);
      }
    }
    short8 af[4], bf[4];
#pragma unroll
    for (int i = 0; i < 4; ++i)
      af[i] = *(short8*)&As[(wm + i * 16 + l15) * 40 + quad * 8];
#pragma unroll
    for (int i = 0; i < 4; ++i)
      bf[i] = *(short8*)&Bs[(wn + i * 16 + l15) * 40 + quad * 8];
#pragma unroll
    for (int i = 0; i < 4; ++i)
#pragma unroll
      for (int j = 0; j < 4; ++j)
        acc[i][j] = __builtin_amdgcn_mfma_f32_16x16x32_bf16(af[i], bf[j], acc[i][j], 0, 0, 0);
  }

  // Epilogue: D lane layout col=lane&15 (n), row=quad*4+e (m)
#pragma unroll
  for (int j = 0; j < 4; ++j) {
    const int gn = bn * 128 + wn + j * 16 + l15;
    const float bv = bih[gn];
#pragma unroll
    for (int i = 0; i < 4; ++i) {
#pragma unroll
      for (int e = 0; e < 4; ++e) {
        int m = bm * 128 + wm + i * 16 + quad * 4 + e;
        int bb = m >> 11, tt = m & 2047;  // m = b*2048 + t
        gi[((size_t)tt * 16 + bb) * 3072 + gn] = f2bf(acc[i][j][e] + bv);
      }
    }
  }
}

// ---------------------------------------------------------------------------
// Kernel 2: persistent GRU scan. 256 WGs x 256 thr, 1 WG/CU (64 KB LDS).
// WG owns 4 hidden units (12 w_hh rows, held in registers). Per step:
// poll flags -> stage h (global->LDS) -> fp32 matvec -> reduce -> gates ->
// publish h slice + release flag.
// ---------------------------------------------------------------------------
__global__ __launch_bounds__(256) void gru_scan(const unsigned short* __restrict__ gi,
                                                const float* __restrict__ whh,
                                                const float* __restrict__ bhh,
                                                float* __restrict__ hpub,
                                                int* __restrict__ flags,
                                                float* __restrict__ out) {
  __shared__ float hs_u[16 * 1024];     // h stage [16][1024]; aliased: red [192][20] at 0, ghs [12][16] at 14080
  float* red = hs_u;
  float* ghs = hs_u + 14080;
  const int tid = threadIdx.x;
  const int wg = blockIdx.x;
  const int u0 = wg * 4;
  const int lane = tid & 63, v = tid >> 6;
  const int rh = v >> 1, bh = v & 1;    // wave = (row-half: 6 rows, batch-half: 8 batches)

  // Load this WG's 12 w_hh rows into registers: wreg[j][c] = w[row rh*6+j][c*256 + lane*4 .. +3]
  float4 wreg[6][4];
#pragma unroll
  for (int j = 0; j < 6; ++j) {
    int jg = rh * 6 + j;                 // 0..11: gate g = jg>>2, unit uu = jg&3
    int g = jg >> 2, uu = jg & 3;
    const float* wp = whh + (size_t)(g * 1024 + u0 + uu) * 1024;
#pragma unroll
    for (int c = 0; c < 4; ++c) wreg[j][c] = *(const float4*)(wp + c * 256 + lane * 4);
  }
  const int fb = tid >> 2, fu = tid & 3;  // gate-thread mapping (tid<64): batch, unit
  float bh_r = 0.f, bh_z = 0.f, bh_n = 0.f, hp = 0.f;
  if (tid < 64) {
    bh_r = bhh[u0 + fu];
    bh_z = bhh[1024 + u0 + fu];
    bh_n = bhh[2048 + u0 + fu];
  }
  int budget = 1 << 23;  // global spin budget: hang-proofing

#pragma unroll 1
  for (int t = 0; t < 2048; ++t) {
    // Prefetch gi for this step (independent of flags -> hides L3/HBM latency)
    unsigned short g0 = 0, g1 = 0, g2 = 0;
    if (tid < 64) {
      const unsigned short* gp = gi + ((size_t)t * 16 + fb) * 3072 + u0 + fu;
      g0 = gp[0]; g1 = gp[1024]; g2 = gp[2048];
    }

    if (t > 0) {
      // Poll: thread i waits for WG i's h slice (acquire, agent scope)
      const int* fl = flags + tid * 16;
      while (__hip_atomic_load(fl, __ATOMIC_ACQUIRE, __HIP_MEMORY_SCOPE_AGENT) < t) {
        if (--budget < 0) break;
      }
      __syncthreads();
      // Stage h_t: 64 KB global -> LDS, fully coalesced
      const float* src = hpub + (t & 1) * 16384;
#pragma unroll
      for (int s2 = 0; s2 < 16; ++s2) {
        int f = (s2 * 256 + tid) * 4;
        *(float4*)&hs_u[f] = *(const float4*)&src[f];
      }
      __syncthreads();
      // Matvec: acc[j][b] partial over lane's k-chunks (k = c*256 + lane*4)
      float acc[6][8];
#pragma unroll
      for (int j = 0; j < 6; ++j)
#pragma unroll
        for (int b = 0; b < 8; ++b) acc[j][b] = 0.f;
#pragma unroll
      for (int c = 0; c < 4; ++c) {
        const int kb = c * 256 + lane * 4;
#pragma unroll
        for (int b = 0; b < 8; ++b) {
          float4 h4 = *(float4*)&hs_u[(bh * 8 + b) * 1024 + kb];
#pragma unroll
          for (int j = 0; j < 6; ++j) {
            float4 w4 = wreg[j][c];
            float a = acc[j][b];
            a = fmaf(w4.x, h4.x, a); a = fmaf(w4.y, h4.y, a);
            a = fmaf(w4.z, h4.z, a); a = fmaf(w4.w, h4.w, a);
            acc[j][b] = a;
          }
        }
      }
      __syncthreads();  // h reads done; red aliases hs_u
      // Reduce: 2-stage butterfly (4-lane groups) then 16 partials to LDS
#pragma unroll
      for (int j = 0; j < 6; ++j) {
#pragma unroll
        for (int b = 0; b < 8; ++b) {
          float s = acc[j][b];
          s += __shfl_xor(s, 1, 64);
          s += __shfl_xor(s, 2, 64);
          if ((lane & 3) == 0) {
            int jb = (rh * 6 + j) * 16 + bh * 8 + b;
            red[jb * 20 + (lane >> 2)] = s;
          }
        }
      }
      __syncthreads();
      if (tid < 192) {
        float s = 0.f;
#pragma unroll
        for (int q = 0; q < 4; ++q) {
          float4 vv = *(float4*)&red[tid * 20 + q * 4];
          s += vv.x + vv.y + vv.z + vv.w;
        }
        ghs[tid] = s;  // ghs[j*16 + b], j = gate*4 + unit
      }
      __syncthreads();
    }

    // Gates + state update + publish (64 threads: (fb, fu))
    if (tid < 64) {
      float ghr = bh_r, ghz = bh_z, ghn = bh_n;
      if (t > 0) {
        ghr += ghs[fu * 16 + fb];
        ghz += ghs[(4 + fu) * 16 + fb];
        ghn += ghs[(8 + fu) * 16 + fb];
      }
      float rr = 1.f / (1.f + __expf(-(bf2f(g0) + ghr)));
      float zz = 1.f / (1.f + __expf(-(bf2f(g1) + ghz)));
      float nn = tanhf(bf2f(g2) + rr * ghn);
      float hnew = (1.f - zz) * nn + zz * hp;
      hp = hnew;  // exact fp32 carry in-register
      out[((size_t)fb * 2048 + t) * 1024 + u0 + fu] = hnew;
      hpub[((t + 1) & 1) * 16384 + fb * 1024 + u0 + fu] = hnew;
      __threadfence();  // writes visible at agent scope before flag release
    }
    __syncthreads();
    if (tid == 0)
      __hip_atomic_store(flags + wg * 16, t + 1, __ATOMIC_RELEASE, __HIP_MEMORY_SCOPE_AGENT);
  }
}

// ---------------------------------------------------------------------------
extern "C" void kernel_launch(void* const* d_in, const int* in_sizes, int n_in,
                              void* d_out, int out_size, void* d_ws, size_t ws_size,
                              hipStream_t stream) {
  const float* h_enc = (const float*)d_in[0];
  const float* w_ih  = (const float*)d_in[1];
  const float* w_hh  = (const float*)d_in[2];
  const float* b_ih  = (const float*)d_in[3];
  const float* b_hh  = (const float*)d_in[4];
  float* out = (float*)d_out;

  const size_t GI_BYTES   = (size_t)2048 * 16 * 3072 * 2;  // 201326592
  const size_t HPUB_BYTES = 2 * 16 * 1024 * 4;             // 131072
  unsigned short* gi = (unsigned short*)d_ws;
  float* hpub = (float*)((char*)d_ws + GI_BYTES);
  int* flags  = (int*)((char*)d_ws + GI_BYTES + HPUB_BYTES);

  hipMemsetAsync(flags, 0, 256 * 16 * sizeof(int), stream);  // flags must start at 0 (ws poisoned 0xAA)

  hipLaunchKernelGGL(gi_gemm, dim3(256, 24), dim3(256), 0, stream, h_enc, w_ih, b_ih, gi);
  hipLaunchKernelGGL(gru_scan, dim3(256), dim3(256), 0, stream, gi, w_hh, b_hh, hpub, flags, out);
}

// Round 2
// 35035.559 us; speedup vs baseline: 2.0342x; 2.0342x over previous
//
#include <hip/hip_runtime.h>
#include <cstdint>

// B=16, T=2048, H=1024, 3H=3072.
// ws layout: gi (bf16, [T][B][3H]) 201326592 B | hpub (fp32, [2][16][1024]) 131072 B | flags (256 int) 1024 B
// d_out doubles as scratch before the scan overwrites it:
//   bytes [0, 67108864)          : h_enc as bf16  [32768][1024]
//   bytes [67108864, 73400320)   : w_ih  as bf16  [3072][1024]

using short8 = __attribute__((ext_vector_type(8))) short;
using f32x4v = __attribute__((ext_vector_type(4))) float;
typedef unsigned long long ull;

__device__ __forceinline__ unsigned short f2bf(float f) {
  unsigned u = __float_as_uint(f);
  unsigned r = (u + 0x7FFFu + ((u >> 16) & 1u)) >> 16;  // RNE
  return (unsigned short)r;
}
__device__ __forceinline__ float bf2f(unsigned short s) {
  return __uint_as_float(((unsigned)s) << 16);
}

// ---------------------------------------------------------------------------
// Kernel 0: one-shot fp32 -> bf16 convert (4 elems/thread, 8B stores)
// ---------------------------------------------------------------------------
__global__ __launch_bounds__(256) void cvt_bf16(const float* __restrict__ src,
                                                ull* __restrict__ dst, int n4) {
  int i = blockIdx.x * blockDim.x + threadIdx.x;
  if (i >= n4) return;
  float4 v = ((const float4*)src)[i];
  ull r = (ull)f2bf(v.x) | ((ull)f2bf(v.y) << 16) | ((ull)f2bf(v.z) << 32) |
          ((ull)f2bf(v.w) << 48);
  dst[i] = r;
}

// ---------------------------------------------------------------------------
// Kernel 1: gi = h_enc @ w_ih^T + b_ih  (pure-bf16 MFMA; inputs pre-converted)
// A = bf16 [M=32768][K=1024] (m = b*2048 + t), W = bf16 [N=3072][K=1024]
// C stored bf16 at gi[(t*16 + b)*3072 + n]
// ---------------------------------------------------------------------------
__global__ __launch_bounds__(256) void gi_gemm(const unsigned short* __restrict__ A,
                                               const unsigned short* __restrict__ W,
                                               const float* __restrict__ bih,
                                               unsigned short* __restrict__ gi) {
  __shared__ unsigned short As[128 * 40];  // 128 rows x 32 bf16, stride 40
  __shared__ unsigned short Bs[128 * 40];
  const int tid = threadIdx.x;
  const int bm = blockIdx.x, bn = blockIdx.y;
  const int row = tid >> 1, colg = (tid & 1) * 16;
  const unsigned short* Ap = A + (size_t)(bm * 128 + row) * 1024 + colg;
  const unsigned short* Bp = W + (size_t)(bn * 128 + row) * 1024 + colg;
  short8 a0 = *(const short8*)Ap, a1 = *(const short8*)(Ap + 8);
  short8 b0 = *(const short8*)Bp, b1 = *(const short8*)(Bp + 8);

  const int lane = tid & 63, wid = tid >> 6;
  const int quad = lane >> 4, l15 = lane & 15;
  const int wm = (wid >> 1) * 64, wn = (wid & 1) * 64;
  f32x4v acc[4][4];
#pragma unroll
  for (int i = 0; i < 4; ++i)
#pragma unroll
    for (int j = 0; j < 4; ++j) acc[i][j] = (f32x4v){0.f, 0.f, 0.f, 0.f};

#pragma unroll 1
  for (int kt = 0; kt < 32; ++kt) {
    __syncthreads();
    *(short8*)&As[row * 40 + colg] = a0;
    *(short8*)&As[row * 40 + colg + 8] = a1;
    *(short8*)&Bs[row * 40 + colg] = b0;
    *(short8*)&Bs[row * 40 + colg + 8] = b1;
    __syncthreads();
    if (kt < 31) {
      Ap += 32; Bp += 32;
      a0 = *(const short8*)Ap; a1 = *(const short8*)(Ap + 8);
      b0 = *(const short8*)Bp; b1 = *(const short8*)(Bp + 8);
    }
    short8 af[4], bf[4];
#pragma unroll
    for (int i = 0; i < 4; ++i)
      af[i] = *(short8*)&As[(wm + i * 16 + l15) * 40 + quad * 8];
#pragma unroll
    for (int i = 0; i < 4; ++i)
      bf[i] = *(short8*)&Bs[(wn + i * 16 + l15) * 40 + quad * 8];
#pragma unroll
    for (int i = 0; i < 4; ++i)
#pragma unroll
      for (int j = 0; j < 4; ++j)
        acc[i][j] = __builtin_amdgcn_mfma_f32_16x16x32_bf16(af[i], bf[j], acc[i][j], 0, 0, 0);
  }

  // D layout: col = lane&15 (n), row = quad*4 + e (m)
#pragma unroll
  for (int j = 0; j < 4; ++j) {
    const int gn = bn * 128 + wn + j * 16 + l15;
    const float bv = bih[gn];
#pragma unroll
    for (int i = 0; i < 4; ++i) {
#pragma unroll
      for (int e = 0; e < 4; ++e) {
        int m = bm * 128 + wm + i * 16 + quad * 4 + e;
        int bb = m >> 11, tt = m & 2047;  // m = b*2048 + t
        gi[((size_t)tt * 16 + bb) * 3072 + gn] = f2bf(acc[i][j][e] + bv);
      }
    }
  }
}

// ---------------------------------------------------------------------------
// Kernel 2: persistent GRU scan. 256 WGs x 256 thr. WG owns 4 hidden units
// (12 w_hh rows in registers). Cross-WG protocol, NO fences in the loop:
//   publish: relaxed agent atomic stores (IF$-bypass) -> s_waitcnt(0) ->
//            relaxed flag store.
//   consume: wave 0 polls ALL 256 flags (2 b64 relaxed loads/lane +
//            shuffle-min) -> stage h via relaxed b64 loads -> LDS.
// ---------------------------------------------------------------------------
__global__ __launch_bounds__(256) void gru_scan(const unsigned short* __restrict__ gi,
                                                const float* __restrict__ whh,
                                                const float* __restrict__ bhh,
                                                float* __restrict__ hpub,
                                                int* __restrict__ flags,
                                                float* __restrict__ out) {
  __shared__ float hs_u[16 * 1024];  // h stage [16][1024]; aliased: red [192][20] at 0, ghs [12][16] at 14080
  float* red = hs_u;
  float* ghs = hs_u + 14080;
  const int tid = threadIdx.x;
  const int wg = blockIdx.x;
  const int u0 = wg * 4;
  const int lane = tid & 63, v = tid >> 6;
  const int rh = v >> 1, bh = v & 1;  // wave = (row-half: 6 rows, batch-half: 8 batches)

  // wreg[j][c] = w_hh[row rh*6+j][c*256 + lane*4 .. +3]
  float4 wreg[6][4];
#pragma unroll
  for (int j = 0; j < 6; ++j) {
    int jg = rh * 6 + j;  // gate g = jg>>2, unit uu = jg&3
    int g = jg >> 2, uu = jg & 3;
    const float* wp = whh + (size_t)(g * 1024 + u0 + uu) * 1024;
#pragma unroll
    for (int c = 0; c < 4; ++c) wreg[j][c] = *(const float4*)(wp + c * 256 + lane * 4);
  }
  const int fb = tid >> 2, fu = tid & 3;  // gate-thread mapping (tid<64)
  float bh_r = 0.f, bh_z = 0.f, bh_n = 0.f, hp = 0.f;
  if (tid < 64) {
    bh_r = bhh[u0 + fu];
    bh_z = bhh[1024 + u0 + fu];
    bh_n = bhh[2048 + u0 + fu];
  }
  int budget = 1 << 22;  // spin budget: hang-proofing

#pragma unroll 1
  for (int t = 0; t < 2048; ++t) {
    // Prefetch gi for this step (normal cached loads; no invalidates anywhere now)
    unsigned short g0 = 0, g1 = 0, g2 = 0;
    if (tid < 64) {
      const unsigned short* gp = gi + ((size_t)t * 16 + fb) * 3072 + u0 + fu;
      g0 = gp[0]; g1 = gp[1024]; g2 = gp[2048];
    }

    if (t > 0) {
      // Wave 0 polls all 256 flags: min over 4 flags/lane, shuffle-min across wave
      if (tid < 64) {
        ull* f8 = (ull*)flags;
        for (;;) {
          ull a = __hip_atomic_load(&f8[tid], __ATOMIC_RELAXED, __HIP_MEMORY_SCOPE_AGENT);
          ull b = __hip_atomic_load(&f8[64 + tid], __ATOMIC_RELAXED, __HIP_MEMORY_SCOPE_AGENT);
          int m = (int)(a & 0xffffffffu), x;
          x = (int)(a >> 32); m = x < m ? x : m;
          x = (int)(b & 0xffffffffu); m = x < m ? x : m;
          x = (int)(b >> 32); m = x < m ? x : m;
#pragma unroll
          for (int k = 1; k < 64; k <<= 1) { x = __shfl_xor(m, k, 64); m = x < m ? x : m; }
          if (m >= t) break;
          if (--budget < 0) break;
        }
      }
      __syncthreads();
      // Stage h_t: 64 KB -> LDS via relaxed agent b64 loads (coherent, IF$-bypass)
      {
        ull* dst = (ull*)hs_u;
        ull* src = (ull*)(hpub + (t & 1) * 16384);
#pragma unroll
        for (int s = 0; s < 32; ++s)
          dst[s * 256 + tid] =
              __hip_atomic_load(&src[s * 256 + tid], __ATOMIC_RELAXED, __HIP_MEMORY_SCOPE_AGENT);
      }
      __syncthreads();
      // Matvec: acc[j][b] partials over lane's k-chunks (k = c*256 + lane*4)
      float acc[6][8];
#pragma unroll
      for (int j = 0; j < 6; ++j)
#pragma unroll
        for (int b = 0; b < 8; ++b) acc[j][b] = 0.f;
#pragma unroll
      for (int c = 0; c < 4; ++c) {
        const int kb = c * 256 + lane * 4;
#pragma unroll
        for (int b = 0; b < 8; ++b) {
          float4 h4 = *(float4*)&hs_u[(bh * 8 + b) * 1024 + kb];
#pragma unroll
          for (int j = 0; j < 6; ++j) {
            float4 w4 = wreg[j][c];
            float a = acc[j][b];
            a = fmaf(w4.x, h4.x, a); a = fmaf(w4.y, h4.y, a);
            a = fmaf(w4.z, h4.z, a); a = fmaf(w4.w, h4.w, a);
            acc[j][b] = a;
          }
        }
      }
      __syncthreads();  // h reads done; red aliases hs_u
      // Reduce: 2-stage butterfly (4-lane groups) then 16 partials to LDS
#pragma unroll
      for (int j = 0; j < 6; ++j) {
#pragma unroll
        for (int b = 0; b < 8; ++b) {
          float s = acc[j][b];
          s += __shfl_xor(s, 1, 64);
          s += __shfl_xor(s, 2, 64);
          if ((lane & 3) == 0) {
            int jb = (rh * 6 + j) * 16 + bh * 8 + b;
            red[jb * 20 + (lane >> 2)] = s;
          }
        }
      }
      __syncthreads();
      if (tid < 192) {
        float s = 0.f;
#pragma unroll
        for (int q = 0; q < 4; ++q) {
          float4 vv = *(float4*)&red[tid * 20 + q * 4];
          s += vv.x + vv.y + vv.z + vv.w;
        }
        ghs[tid] = s;  // ghs[j*16 + b], j = gate*4 + unit
      }
      __syncthreads();
    }

    // Gates + state update + publish (wave 0 only: threads (fb, fu))
    if (tid < 64) {
      float ghr = bh_r, ghz = bh_z, ghn = bh_n;
      if (t > 0) {
        ghr += ghs[fu * 16 + fb];
        ghz += ghs[(4 + fu) * 16 + fb];
        ghn += ghs[(8 + fu) * 16 + fb];
      }
      float rr = 1.f / (1.f + __expf(-(bf2f(g0) + ghr)));
      float zz = 1.f / (1.f + __expf(-(bf2f(g1) + ghz)));
      float nn = tanhf(bf2f(g2) + rr * ghn);
      float hnew = (1.f - zz) * nn + zz * hp;
      hp = hnew;  // exact fp32 carry in-register
      out[((size_t)fb * 2048 + t) * 1024 + u0 + fu] = hnew;
      __hip_atomic_store(&hpub[((t + 1) & 1) * 16384 + fb * 1024 + u0 + fu], hnew,
                         __ATOMIC_RELAXED, __HIP_MEMORY_SCOPE_AGENT);
    }
    // Order: h stores complete at coherence point before flag release (wave 0).
    __builtin_amdgcn_s_waitcnt(0);
    if (tid == 0)
      __hip_atomic_store(&flags[wg], t + 1, __ATOMIC_RELAXED, __HIP_MEMORY_SCOPE_AGENT);
  }
}

// ---------------------------------------------------------------------------
extern "C" void kernel_launch(void* const* d_in, const int* in_sizes, int n_in,
                              void* d_out, int out_size, void* d_ws, size_t ws_size,
                              hipStream_t stream) {
  const float* h_enc = (const float*)d_in[0];
  const float* w_ih  = (const float*)d_in[1];
  const float* w_hh  = (const float*)d_in[2];
  const float* b_ih  = (const float*)d_in[3];
  const float* b_hh  = (const float*)d_in[4];
  float* out = (float*)d_out;

  const size_t GI_BYTES   = (size_t)2048 * 16 * 3072 * 2;  // 201326592
  const size_t HPUB_BYTES = 2 * 16 * 1024 * 4;             // 131072
  unsigned short* gi = (unsigned short*)d_ws;
  float* hpub = (float*)((char*)d_ws + GI_BYTES);
  int* flags  = (int*)((char*)d_ws + GI_BYTES + HPUB_BYTES);

  // d_out as scratch for bf16 inputs (scan overwrites every element later)
  unsigned short* a_bf = (unsigned short*)d_out;                        // 67108864 B
  unsigned short* w_bf = (unsigned short*)((char*)d_out + 67108864);    // 6291456 B

  hipMemsetAsync(flags, 0, 256 * sizeof(int), stream);  // flags must start at 0

  hipLaunchKernelGGL(cvt_bf16, dim3(32768), dim3(256), 0, stream, h_enc, (ull*)a_bf, 8388608);
  hipLaunchKernelGGL(cvt_bf16, dim3(3072), dim3(256), 0, stream, w_ih, (ull*)w_bf, 786432);
  hipLaunchKernelGGL(gi_gemm, dim3(256, 24), dim3(256), 0, stream, a_bf, w_bf, b_ih, gi);
  hipLaunchKernelGGL(gru_scan, dim3(256), dim3(256), 0, stream, gi, w_hh, b_hh, hpub, flags, out);
}

// Round 3
// 27586.591 us; speedup vs baseline: 2.5834x; 1.2700x over previous
//
#include <hip/hip_runtime.h>
#include <cstdint>

// B=16, T=2048, H=1024, 3H=3072.
// ws layout: gi (bf16, [T][B][3H]) 201326592 B | hpub (tagged ull, [2][16][1024]) 262144 B
// d_out doubles as scratch before the scan overwrites it:
//   bytes [0, 67108864)          : h_enc as bf16  [32768][1024]
//   bytes [67108864, 73400320)   : w_ih  as bf16  [3072][1024]

using short8 = __attribute__((ext_vector_type(8))) short;
using f32x4v = __attribute__((ext_vector_type(4))) float;
typedef unsigned long long ull;

__device__ __forceinline__ unsigned short f2bf(float f) {
  unsigned u = __float_as_uint(f);
  unsigned r = (u + 0x7FFFu + ((u >> 16) & 1u)) >> 16;  // RNE
  return (unsigned short)r;
}
__device__ __forceinline__ float bf2f(unsigned short s) {
  return __uint_as_float(((unsigned)s) << 16);
}

// ---------------------------------------------------------------------------
// Kernel 0: one-shot fp32 -> bf16 convert (4 elems/thread, 8B stores)
// ---------------------------------------------------------------------------
__global__ __launch_bounds__(256) void cvt_bf16(const float* __restrict__ src,
                                                ull* __restrict__ dst, int n4) {
  int i = blockIdx.x * blockDim.x + threadIdx.x;
  if (i >= n4) return;
  float4 v = ((const float4*)src)[i];
  ull r = (ull)f2bf(v.x) | ((ull)f2bf(v.y) << 16) | ((ull)f2bf(v.z) << 32) |
          ((ull)f2bf(v.w) << 48);
  dst[i] = r;
}

// ---------------------------------------------------------------------------
// Kernel 1: gi = h_enc @ w_ih^T + b_ih  (pure-bf16 MFMA; inputs pre-converted)
// ---------------------------------------------------------------------------
__global__ __launch_bounds__(256) void gi_gemm(const unsigned short* __restrict__ A,
                                               const unsigned short* __restrict__ W,
                                               const float* __restrict__ bih,
                                               unsigned short* __restrict__ gi) {
  __shared__ unsigned short As[128 * 40];
  __shared__ unsigned short Bs[128 * 40];
  const int tid = threadIdx.x;
  const int bm = blockIdx.x, bn = blockIdx.y;
  const int row = tid >> 1, colg = (tid & 1) * 16;
  const unsigned short* Ap = A + (size_t)(bm * 128 + row) * 1024 + colg;
  const unsigned short* Bp = W + (size_t)(bn * 128 + row) * 1024 + colg;
  short8 a0 = *(const short8*)Ap, a1 = *(const short8*)(Ap + 8);
  short8 b0 = *(const short8*)Bp, b1 = *(const short8*)(Bp + 8);

  const int lane = tid & 63, wid = tid >> 6;
  const int quad = lane >> 4, l15 = lane & 15;
  const int wm = (wid >> 1) * 64, wn = (wid & 1) * 64;
  f32x4v acc[4][4];
#pragma unroll
  for (int i = 0; i < 4; ++i)
#pragma unroll
    for (int j = 0; j < 4; ++j) acc[i][j] = (f32x4v){0.f, 0.f, 0.f, 0.f};

#pragma unroll 1
  for (int kt = 0; kt < 32; ++kt) {
    __syncthreads();
    *(short8*)&As[row * 40 + colg] = a0;
    *(short8*)&As[row * 40 + colg + 8] = a1;
    *(short8*)&Bs[row * 40 + colg] = b0;
    *(short8*)&Bs[row * 40 + colg + 8] = b1;
    __syncthreads();
    if (kt < 31) {
      Ap += 32; Bp += 32;
      a0 = *(const short8*)Ap; a1 = *(const short8*)(Ap + 8);
      b0 = *(const short8*)Bp; b1 = *(const short8*)(Bp + 8);
    }
    short8 af[4], bf[4];
#pragma unroll
    for (int i = 0; i < 4; ++i)
      af[i] = *(short8*)&As[(wm + i * 16 + l15) * 40 + quad * 8];
#pragma unroll
    for (int i = 0; i < 4; ++i)
      bf[i] = *(short8*)&Bs[(wn + i * 16 + l15) * 40 + quad * 8];
#pragma unroll
    for (int i = 0; i < 4; ++i)
#pragma unroll
      for (int j = 0; j < 4; ++j)
        acc[i][j] = __builtin_amdgcn_mfma_f32_16x16x32_bf16(af[i], bf[j], acc[i][j], 0, 0, 0);
  }

  // D layout: col = lane&15 (n), row = quad*4 + e (m)
#pragma unroll
  for (int j = 0; j < 4; ++j) {
    const int gn = bn * 128 + wn + j * 16 + l15;
    const float bv = bih[gn];
#pragma unroll
    for (int i = 0; i < 4; ++i) {
#pragma unroll
      for (int e = 0; e < 4; ++e) {
        int m = bm * 128 + wm + i * 16 + quad * 4 + e;
        int bb = m >> 11, tt = m & 2047;  // m = b*2048 + t
        gi[((size_t)tt * 16 + bb) * 3072 + gn] = f2bf(acc[i][j][e] + bv);
      }
    }
  }
}

// ---------------------------------------------------------------------------
// Kernel 2: persistent GRU scan. 256 WGs x 256 thr. WG owns 4 hidden units
// (12 w_hh rows in registers). Sync protocol: NO flags, NO fences.
// h is published as self-validating tagged 8B atoms: (step_tag<<32)|f32(h).
// Producers: relaxed agent-scope 8B stores. Consumers: relaxed agent-scope
// 8B loads, retry chunks whose tag != t. Double-buffered by step parity
// (publish skew across WGs is provably <= 1 step, so exact-tag match is safe).
// ---------------------------------------------------------------------------
__global__ __launch_bounds__(256) void gru_scan(const unsigned short* __restrict__ gi,
                                                const float* __restrict__ whh,
                                                const float* __restrict__ bhh,
                                                ull* __restrict__ hpub,
                                                float* __restrict__ out) {
  __shared__ float hs_u[16 * 1024];  // h stage [16][1024]; aliased: red [192][20] at 0, ghs [12][16] at 14080
  float* red = hs_u;
  float* ghs = hs_u + 14080;
  const int tid = threadIdx.x;
  const int wg = blockIdx.x;
  const int u0 = wg * 4;
  const int lane = tid & 63, v = tid >> 6;
  const int rh = v >> 1, bh = v & 1;  // wave = (row-half: 6 rows, batch-half: 8 batches)

  // wreg[j][c] = w_hh[row rh*6+j][c*256 + lane*4 .. +3]
  float4 wreg[6][4];
#pragma unroll
  for (int j = 0; j < 6; ++j) {
    int jg = rh * 6 + j;  // gate g = jg>>2, unit uu = jg&3
    int g = jg >> 2, uu = jg & 3;
    const float* wp = whh + (size_t)(g * 1024 + u0 + uu) * 1024;
#pragma unroll
    for (int c = 0; c < 4; ++c) wreg[j][c] = *(const float4*)(wp + c * 256 + lane * 4);
  }
  const int fb = tid >> 2, fu = tid & 3;  // gate-thread mapping (tid<64)
  float bh_r = 0.f, bh_z = 0.f, bh_n = 0.f, hp = 0.f;
  if (tid < 64) {
    bh_r = bhh[u0 + fu];
    bh_z = bhh[1024 + u0 + fu];
    bh_n = bhh[2048 + u0 + fu];
  }
  int budget = 1 << 22;  // retry budget (burned only on stale chunks): hang-proofing

#pragma unroll 1
  for (int t = 0; t < 2048; ++t) {
    // Prefetch gi for this step (plain cached loads, latency hidden behind staging)
    unsigned short g0 = 0, g1 = 0, g2 = 0;
    if (tid < 64) {
      const unsigned short* gp = gi + ((size_t)t * 16 + fb) * 3072 + u0 + fu;
      g0 = gp[0]; g1 = gp[1024]; g2 = gp[2048];
    }

    if (t > 0) {
      // Stage h_t: 16384 tagged ulls -> LDS. 64/thread in 8 chunks of 8.
      // Chunk retries independently until all 8 tags == t.
      const ull* src = hpub + (size_t)(t & 1) * 16384;
#pragma unroll 1
      for (int s = 0; s < 8; ++s) {
        const int base = s * 8;
        ull vv[8];
        int bad;
        do {
          bad = 0;
#pragma unroll
          for (int j = 0; j < 8; ++j)
            vv[j] = __hip_atomic_load(&src[(base + j) * 256 + tid], __ATOMIC_RELAXED,
                                      __HIP_MEMORY_SCOPE_AGENT);
#pragma unroll
          for (int j = 0; j < 8; ++j) bad |= ((int)(vv[j] >> 32) != t);
        } while (bad && --budget > 0);
#pragma unroll
        for (int j = 0; j < 8; ++j)
          hs_u[(base + j) * 256 + tid] = __uint_as_float((unsigned)vv[j]);
      }
      __syncthreads();
      // Matvec: acc[j][b] partials over lane's k-chunks (k = c*256 + lane*4)
      float acc[6][8];
#pragma unroll
      for (int j = 0; j < 6; ++j)
#pragma unroll
        for (int b = 0; b < 8; ++b) acc[j][b] = 0.f;
#pragma unroll
      for (int c = 0; c < 4; ++c) {
        const int kb = c * 256 + lane * 4;
#pragma unroll
        for (int b = 0; b < 8; ++b) {
          float4 h4 = *(float4*)&hs_u[(bh * 8 + b) * 1024 + kb];
#pragma unroll
          for (int j = 0; j < 6; ++j) {
            float4 w4 = wreg[j][c];
            float a = acc[j][b];
            a = fmaf(w4.x, h4.x, a); a = fmaf(w4.y, h4.y, a);
            a = fmaf(w4.z, h4.z, a); a = fmaf(w4.w, h4.w, a);
            acc[j][b] = a;
          }
        }
      }
      __syncthreads();  // h reads done; red aliases hs_u
      // Reduce: 2-stage butterfly (4-lane groups) then 16 partials to LDS
#pragma unroll
      for (int j = 0; j < 6; ++j) {
#pragma unroll
        for (int b = 0; b < 8; ++b) {
          float s = acc[j][b];
          s += __shfl_xor(s, 1, 64);
          s += __shfl_xor(s, 2, 64);
          if ((lane & 3) == 0) {
            int jb = (rh * 6 + j) * 16 + bh * 8 + b;
            red[jb * 20 + (lane >> 2)] = s;
          }
        }
      }
      __syncthreads();
      if (tid < 192) {
        float s = 0.f;
#pragma unroll
        for (int q = 0; q < 4; ++q) {
          float4 vv2 = *(float4*)&red[tid * 20 + q * 4];
          s += vv2.x + vv2.y + vv2.z + vv2.w;
        }
        ghs[tid] = s;  // ghs[j*16 + b], j = gate*4 + unit
      }
      __syncthreads();
    }

    // Gates + state update + publish (wave 0 only: threads (fb, fu))
    if (tid < 64) {
      float ghr = bh_r, ghz = bh_z, ghn = bh_n;
      if (t > 0) {
        ghr += ghs[fu * 16 + fb];
        ghz += ghs[(4 + fu) * 16 + fb];
        ghn += ghs[(8 + fu) * 16 + fb];
      }
      float rr = 1.f / (1.f + __expf(-(bf2f(g0) + ghr)));
      float zz = 1.f / (1.f + __expf(-(bf2f(g1) + ghz)));
      float nn = tanhf(bf2f(g2) + rr * ghn);
      float hnew = (1.f - zz) * nn + zz * hp;
      hp = hnew;  // exact fp32 carry in-register
      out[((size_t)fb * 2048 + t) * 1024 + u0 + fu] = hnew;
      // Self-validating publish: tag (t+1) packed with the value, single 8B atom.
      ull pv = (ull)__float_as_uint(hnew) | ((ull)(unsigned)(t + 1) << 32);
      __hip_atomic_store(&hpub[((size_t)((t + 1) & 1)) * 16384 + fb * 1024 + u0 + fu], pv,
                         __ATOMIC_RELAXED, __HIP_MEMORY_SCOPE_AGENT);
    }
    // No fence, no waitcnt, no flag: consumers self-validate via tags.
  }
}

// ---------------------------------------------------------------------------
extern "C" void kernel_launch(void* const* d_in, const int* in_sizes, int n_in,
                              void* d_out, int out_size, void* d_ws, size_t ws_size,
                              hipStream_t stream) {
  const float* h_enc = (const float*)d_in[0];
  const float* w_ih  = (const float*)d_in[1];
  const float* w_hh  = (const float*)d_in[2];
  const float* b_ih  = (const float*)d_in[3];
  const float* b_hh  = (const float*)d_in[4];
  float* out = (float*)d_out;

  const size_t GI_BYTES = (size_t)2048 * 16 * 3072 * 2;  // 201326592
  unsigned short* gi = (unsigned short*)d_ws;
  ull* hpub = (ull*)((char*)d_ws + GI_BYTES);  // [2][16][1024] tagged, 262144 B
  // hpub needs no init: poison tag 0xAAAAAAAA never matches a real step tag.

  // d_out as scratch for bf16 inputs (scan overwrites every element later)
  unsigned short* a_bf = (unsigned short*)d_out;                      // 67108864 B
  unsigned short* w_bf = (unsigned short*)((char*)d_out + 67108864);  // 6291456 B

  hipLaunchKernelGGL(cvt_bf16, dim3(32768), dim3(256), 0, stream, h_enc, (ull*)a_bf, 8388608);
  hipLaunchKernelGGL(cvt_bf16, dim3(3072), dim3(256), 0, stream, w_ih, (ull*)w_bf, 786432);
  hipLaunchKernelGGL(gi_gemm, dim3(256, 24), dim3(256), 0, stream, a_bf, w_bf, b_ih, gi);
  hipLaunchKernelGGL(gru_scan, dim3(256), dim3(256), 0, stream, gi, w_hh, b_hh, hpub, out);
}